// Round 1
// 394.415 us; speedup vs baseline: 1.0706x; 1.0706x over previous
//
#include <hip/hip_runtime.h>
#include <cstdint>
#include <cstddef>

// Problem constants
#define B_ROWS 16384
#define FEAT   2048
#define FIELD  32
#define KDIM   64
#define NCOLS  2048           // FIELD*KDIM (main quadratic columns)
#define NAUG   2176           // 2048 + 64 (vsum) + 1 (w) + 63 zero-pad = 17*128

using half8   = __attribute__((ext_vector_type(8))) _Float16;
using half4   = __attribute__((ext_vector_type(4))) _Float16;
using floatx4 = __attribute__((ext_vector_type(4))) float;

// Async global->LDS, 16B per lane. LDS dest must be wave-uniform base + lane*16.
__device__ __forceinline__ void load_lds16(const void* g, void* l) {
  __builtin_amdgcn_global_load_lds((const __attribute__((address_space(1))) void*)g,
                                   (__attribute__((address_space(3))) void*)l, 16, 0, 0);
}

// --- fused prep: one launch does everything the gemm needs -----------------
// blocks [0,8192):      x fp32 -> xh fp16, 16 floats/thread
// blocks [8192,9216):   v[f][n] -> vt[n][f] fp16 transpose (64x64 tiles)
// blocks [9216,9728):   vsum rows vt[2048+k][f] = sum_s v[f][s*64+k]
// blocks [9728,10240):  w row (2112) + zero rows (2113..2175)
// blocks [10240,10304): zero arg[16384]
__global__ __launch_bounds__(256) void k_prep(const float* __restrict__ x,
                                              const float* __restrict__ v,
                                              const float* __restrict__ w,
                                              _Float16* __restrict__ xh,
                                              _Float16* __restrict__ vt,
                                              float* __restrict__ arg) {
  const int bb = blockIdx.x;
  const int t = threadIdx.x;
  if (bb < 8192) {
    size_t i = ((size_t)bb * 256 + t) * 16;
    float4 v0 = *(const float4*)(x + i);
    float4 v1 = *(const float4*)(x + i + 4);
    float4 v2 = *(const float4*)(x + i + 8);
    float4 v3 = *(const float4*)(x + i + 12);
    half8 h0 = { (_Float16)v0.x, (_Float16)v0.y, (_Float16)v0.z, (_Float16)v0.w,
                 (_Float16)v1.x, (_Float16)v1.y, (_Float16)v1.z, (_Float16)v1.w };
    half8 h1 = { (_Float16)v2.x, (_Float16)v2.y, (_Float16)v2.z, (_Float16)v2.w,
                 (_Float16)v3.x, (_Float16)v3.y, (_Float16)v3.z, (_Float16)v3.w };
    *(half8*)(xh + i) = h0;
    *(half8*)(xh + i + 8) = h1;
  } else if (bb < 9216) {
    __shared__ _Float16 tile[64 * 68];
    const int b2 = bb - 8192;
    const int f0 = (b2 >> 5) * 64;
    const int n0 = (b2 & 31) * 64;
#pragma unroll
    for (int j = 0; j < 4; ++j) {
      int c = j * 256 + t;
      int row = c >> 4;                           // f local
      int col = (c & 15) * 4;                     // n local
      float4 val = *(const float4*)(v + (size_t)(f0 + row) * NCOLS + n0 + col);
      tile[row * 68 + col + 0] = (_Float16)val.x;
      tile[row * 68 + col + 1] = (_Float16)val.y;
      tile[row * 68 + col + 2] = (_Float16)val.z;
      tile[row * 68 + col + 3] = (_Float16)val.w;
    }
    __syncthreads();
#pragma unroll
    for (int j = 0; j < 4; ++j) {
      int c = j * 256 + t;
      int nl = c >> 4;                            // n local (row of vt)
      int fl = (c & 15) * 4;                      // f local group of 4
      half4 h = { tile[(fl + 0) * 68 + nl], tile[(fl + 1) * 68 + nl],
                  tile[(fl + 2) * 68 + nl], tile[(fl + 3) * 68 + nl] };
      *(half4*)(vt + (size_t)(n0 + nl) * FEAT + f0 + fl) = h;
    }
  } else if (bb < 9728) {
    const int k = t & 63;
    const int f = (bb - 9216) * 4 + (t >> 6);
    float s = 0.f;
#pragma unroll
    for (int si = 0; si < FIELD; ++si) s += v[(size_t)f * NCOLS + si * KDIM + k];
    vt[(size_t)(NCOLS + k) * FEAT + f] = (_Float16)s;
  } else if (bb < 10240) {
    int idx = (bb - 9728) * 256 + t;              // 64*2048 elements
    int r = NCOLS + KDIM + (idx >> 11);           // 2112..2175
    int f = idx & 2047;
    vt[(size_t)r * FEAT + f] = (r == NCOLS + KDIM) ? (_Float16)w[f] : (_Float16)0.f;
  } else {
    arg[(bb - 10240) * 256 + t] = 0.f;
  }
}

// --- fused GEMM + row-reduce epilogue: 256x256 tile, 8-wave, 8-phase -------
// C = xh[16384x2048] * vt^T (vt is [n][k], k contiguous). Per row m:
//   arg[m] += sum_n coeff(n, C[m,n]);  coeff: n<2048 -> -0.5*c^2,
//   2048<=n<2112 -> +0.5*c^2, n==2112 -> +c, else 0.
//
// Deep-pipelined schedule (T2 swizzle + T3/T4 counted vmcnt + T5 setprio):
//  - K-tile = 64 split into two 32-wide granules (kg0/kg1) per matrix.
//    LDS: 2 buf x {A,B} x {kg0,kg1} granules of 16KB = 128 KiB.
//  - Granule layout: 128 LDS-rows x 128B. Global (row, kc16B) stored at
//    L = row&127, slot = ((row>>7)*4 + kc) ^ (L&7): conflict-free
//    ds_read_b128 (quarter-wave spans all 32 banks) and 64B-run coalesced
//    global_load_lds staging (dest linear, source pre-swizzled).
//  - 4 phases/K-tile (ks half x M-frag half quadrants), 16 MFMA each;
//    one granule staged per phase into a region whose last read was a
//    barrier-separated earlier phase:
//      ph0: stage A(t+1,kg1)   ph1: stage B(t+1,kg1)   (into buf^1)
//      ph2: stage A(t+2,kg0)   ph3: stage B(t+2,kg0)   (into buf, just freed)
//    vmcnt(4) once per K-tile (2 granules in flight; stage->use = 6 phases).
__global__ __launch_bounds__(512, 2) void k_gemm(const _Float16* __restrict__ xh,
                                                 const _Float16* __restrict__ vt,
                                                 float* __restrict__ arg) {
  __shared__ __align__(16) _Float16 lds[65536];   // 128 KiB
  const int tid  = threadIdx.x;
  const int lane = tid & 63;
  const int wave = tid >> 6;      // 0..7
  const int wm   = wave >> 2;     // 0..1 -> M offset wm*128
  const int wn   = wave & 3;      // 0..3 -> N offset wn*64
  const int lr   = lane & 15;     // frag row (A) / col (B)
  const int q    = lane >> 4;     // k-chunk within 32-k granule

  // bijective XCD swizzle (576 = 8*72 exactly); m-fast within each XCD so
  // co-resident blocks on one XCD share the same B panel (L2-hot).
  const int bid = blockIdx.x;
  const int wg  = (bid & 7) * 72 + (bid >> 3);
  const int m0  = (wg & 63) * 256;
  const int n0  = (wg >> 6) * 256;     // 0..8; last block covers cols 2048..2303

  // fragment LDS offsets (halves) within any granule segment.
  // offA[f+4] = offA[f] + 4096 (L jumps by 64, slot unchanged since 64&7==0).
  int offA[4], offB[4];
#pragma unroll
  for (int f = 0; f < 4; ++f) {
    int L = f * 16 + lr;
    int u = wm * 4 + q;
    offA[f] = L * 64 + ((u ^ (L & 7)) * 8);
  }
#pragma unroll
  for (int g = 0; g < 4; ++g) {
    int L = (wn & 1) * 64 + g * 16 + lr;
    int u = (wn >> 1) * 4 + q;
    offB[g] = L * 64 + ((u ^ (L & 7)) * 8);
  }

  // staging source decode: linear chunk c2 = l*512 + tid -> (row, kc).
  // c2 = tid+512 gives row0+64, same kc (since (L+64)&7 == L&7).
  const int L0   = tid >> 3;
  const int u0   = (tid & 7) ^ (L0 & 7);
  const int row0 = (u0 >> 2) * 128 + L0;
  const int kc0  = u0 & 3;
  const _Float16* pA0 = xh + (size_t)(m0 + row0) * FEAT + kc0 * 8;
  const _Float16* pA1 = pA0 + (size_t)64 * FEAT;
  // clamp B rows into vt; rows 2113..2175 are zero rows, so clamped loads
  // stage zeros and cols >= 2176 contribute nothing (coeff 0 anyway).
  const int rb0 = (n0 + row0      < NAUG) ? n0 + row0      : NAUG - 1;
  const int rb1 = (n0 + row0 + 64 < NAUG) ? n0 + row0 + 64 : NAUG - 1;
  const _Float16* pB0 = vt + (size_t)rb0 * FEAT + kc0 * 8;
  const _Float16* pB1 = vt + (size_t)rb1 * FEAT + kc0 * 8;

  auto stageA = [&](int koff, int seg) {
    load_lds16(pA0 + koff, lds + seg + tid * 8);
    load_lds16(pA1 + koff, lds + seg + 4096 + tid * 8);
  };
  auto stageB = [&](int koff, int seg) {
    load_lds16(pB0 + koff, lds + seg + tid * 8);
    load_lds16(pB1 + koff, lds + seg + 4096 + tid * 8);
  };

  floatx4 acc[8][4] = {};
  half8 af[4], bf[4];

  // prologue: K-tile 0 (both granules) + K-tile 1 kg0.
  // segA(buf,kg) = ((buf<<1)|kg)*8192 halves; segB = +32768.
  stageA(0, 0);       stageB(0, 32768);
  stageA(32, 8192);   stageB(32, 40960);
  stageA(64, 16384);  stageB(64, 49152);
  asm volatile("s_waitcnt vmcnt(4)" ::: "memory");  // K-tile 0 fully landed
  __builtin_amdgcn_s_barrier();

#define PHASE_TAIL()                                        \
    __builtin_amdgcn_s_barrier();                           \
    asm volatile("s_waitcnt lgkmcnt(0)" ::: "memory");      \
    __builtin_amdgcn_sched_barrier(0);                      \
    __builtin_amdgcn_s_setprio(1)

#define PHASE_END()                                         \
    __builtin_amdgcn_s_setprio(0);                          \
    __builtin_amdgcn_s_barrier()

#pragma unroll 2
  for (int t = 0; t < 32; ++t) {
    const int sA0  = ((t & 1) << 1) * 8192;                 // segA(buf, kg0)
    const int sB0  = 32768 + sA0;                           // segB(buf, kg0)
    const int sPA1 = ((((t + 1) & 1) << 1) | 1) * 8192;     // segA(buf^1, kg1)

    // ---- phase 0: ks=0, M-frags 0-3 ---------------------------------------
#pragma unroll
    for (int g = 0; g < 4; ++g) bf[g] = *(const half8*)(lds + sB0 + offB[g]);
#pragma unroll
    for (int f = 0; f < 4; ++f) af[f] = *(const half8*)(lds + sA0 + offA[f]);
    if (t < 31) stageA((t + 1) * 64 + 32, sPA1);
    PHASE_TAIL();
#pragma unroll
    for (int f = 0; f < 4; ++f)
#pragma unroll
      for (int g = 0; g < 4; ++g)
        acc[f][g] = __builtin_amdgcn_mfma_f32_16x16x32_f16(af[f], bf[g],
                                                           acc[f][g], 0, 0, 0);
    PHASE_END();

    // ---- phase 1: ks=0, M-frags 4-7 (bf reused) ---------------------------
#pragma unroll
    for (int f = 0; f < 4; ++f) af[f] = *(const half8*)(lds + sA0 + 4096 + offA[f]);
    if (t < 31) stageB((t + 1) * 64 + 32, 32768 + sPA1);
    PHASE_TAIL();
#pragma unroll
    for (int f = 0; f < 4; ++f)
#pragma unroll
      for (int g = 0; g < 4; ++g)
        acc[4 + f][g] = __builtin_amdgcn_mfma_f32_16x16x32_f16(af[f], bf[g],
                                                               acc[4 + f][g], 0, 0, 0);
    PHASE_END();

    // ---- phase 2: ks=32, M-frags 0-3 --------------------------------------
#pragma unroll
    for (int g = 0; g < 4; ++g) bf[g] = *(const half8*)(lds + sB0 + 8192 + offB[g]);
#pragma unroll
    for (int f = 0; f < 4; ++f) af[f] = *(const half8*)(lds + sA0 + 8192 + offA[f]);
    if (t < 30) stageA((t + 2) * 64, sA0);
    PHASE_TAIL();
#pragma unroll
    for (int f = 0; f < 4; ++f)
#pragma unroll
      for (int g = 0; g < 4; ++g)
        acc[f][g] = __builtin_amdgcn_mfma_f32_16x16x32_f16(af[f], bf[g],
                                                           acc[f][g], 0, 0, 0);
    PHASE_END();

    // ---- phase 3: ks=32, M-frags 4-7 + per-K-tile counted vmcnt -----------
#pragma unroll
    for (int f = 0; f < 4; ++f) af[f] = *(const half8*)(lds + sA0 + 12288 + offA[f]);
    if (t < 30) stageB((t + 2) * 64, sB0);
    __builtin_amdgcn_s_barrier();
    asm volatile("s_waitcnt lgkmcnt(0)" ::: "memory");
    __builtin_amdgcn_sched_barrier(0);
    __builtin_amdgcn_s_setprio(1);
#pragma unroll
    for (int f = 0; f < 4; ++f)
#pragma unroll
      for (int g = 0; g < 4; ++g)
        acc[4 + f][g] = __builtin_amdgcn_mfma_f32_16x16x32_f16(af[f], bf[g],
                                                               acc[4 + f][g], 0, 0, 0);
    __builtin_amdgcn_s_setprio(0);
    // steady state: 2 granules (4 loads) in flight across the boundary.
    // t>=30: no q2/q3 stages were issued, so the kg1 stages would stay
    // among the 4 newest -> drain fully instead.
    if (t < 30) { asm volatile("s_waitcnt vmcnt(4)" ::: "memory"); }
    else        { asm volatile("s_waitcnt vmcnt(0)" ::: "memory"); }
    __builtin_amdgcn_sched_barrier(0);
    __builtin_amdgcn_s_barrier();
  }
#undef PHASE_TAIL
#undef PHASE_END

  // Epilogue: C/D layout col=lane&15, row=(lane>>4)*4+reg.
  const int cq = lane >> 4;
  const int mrow = m0 + wm * 128;
  const int ncol = n0 + wn * 64;
#pragma unroll
  for (int f = 0; f < 8; ++f) {
#pragma unroll
    for (int r = 0; r < 4; ++r) {
      float contrib = 0.f;
#pragma unroll
      for (int g = 0; g < 4; ++g) {
        int col = ncol + g * 16 + lr;
        float vv = acc[f][g][r];
        float qv = vv * vv;
        if (col < NCOLS)                contrib -= 0.5f * qv;
        else if (col < NCOLS + KDIM)    contrib += 0.5f * qv;
        else if (col == NCOLS + KDIM)   contrib += vv;
      }
      contrib += __shfl_xor(contrib, 1);
      contrib += __shfl_xor(contrib, 2);
      contrib += __shfl_xor(contrib, 4);
      contrib += __shfl_xor(contrib, 8);
      if (lr == 0) atomicAdd(&arg[mrow + f * 16 + cq * 4 + r], contrib);
    }
  }
}

// --- finalize: sigmoid ------------------------------------------------------
__global__ __launch_bounds__(256) void k_fin(const float* __restrict__ arg,
                                             const float* __restrict__ b,
                                             float* __restrict__ out) {
  int i = blockIdx.x * 256 + threadIdx.x;
  float z = arg[i] + b[0];
  out[i] = 1.f / (1.f + __expf(-z));
}

extern "C" void kernel_launch(void* const* d_in, const int* in_sizes, int n_in,
                              void* d_out, int out_size, void* d_ws, size_t ws_size,
                              hipStream_t stream) {
  const float* x = (const float*)d_in[0];   // [16384, 2048]
  const float* w = (const float*)d_in[1];   // [2048]
  const float* b = (const float*)d_in[2];   // scalar
  const float* v = (const float*)d_in[3];   // [2048, 32, 64]
  float* out = (float*)d_out;               // [16384] fp32

  char* ws = (char*)d_ws;
  _Float16* xh  = (_Float16*)ws;                          // 67,108,864 B
  _Float16* vt  = (_Float16*)(ws + 67108864);             //  8,912,896 B
  float*    arg = (float*)(ws + 67108864 + 8912896);      //     65,536 B

  k_prep<<<10304, 256, 0, stream>>>(x, v, w, xh, vt, arg);
  k_gemm<<<576, 512, 0, stream>>>(xh, vt, arg);
  k_fin<<<64, 256, 0, stream>>>(arg, b, out);
}